// Round 1
// baseline (392.951 us; speedup 1.0000x reference)
//
#include <hip/hip_runtime.h>

// Problem constants
#define BB    8
#define CC    64
#define NN    2048
#define GG    2048      // packed mode count (64 x 32)
#define MFREQ 4032

typedef __attribute__((ext_vector_type(4))) float f32x4;
typedef __attribute__((ext_vector_type(8))) short bf16x8;

static __device__ __forceinline__ unsigned short f2bf(float f) {
    union { float f; unsigned u; } v; v.f = f;
    unsigned r = v.u + 0x7fff + ((v.u >> 16) & 1);   // RNE
    return (unsigned short)(r >> 16);
}

static __device__ __forceinline__ bf16x8 as_bf16x8(uint4 u) {
    union { uint4 u; bf16x8 b; } v; v.u = u; return v.b;
}

// ---------------------------------------------------------------------------
// Pack Af [4096 x 2048] bf16: rows 0..2047 = Vf_re[f(g)], rows 2048.. = Vf_im
// f(g) = (g>>5)*63 + (g&31)
__global__ __launch_bounds__(256) void pack_af(const float* __restrict__ vf_re,
                                               const float* __restrict__ vf_im,
                                               unsigned short* __restrict__ af) {
    int idx = blockIdx.x * 256 + threadIdx.x;      // one quad (4 floats)
    int m = idx >> 9;                               // 512 quads per row
    int q = (idx & 511) * 4;
    int g = m & 2047;
    int f = (g >> 5) * 63 + (g & 31);
    const float* src = (m < 2048 ? vf_re : vf_im) + (size_t)f * 2048 + q;
    float4 v = *(const float4*)src;
    ushort4 o; o.x = f2bf(v.x); o.y = f2bf(v.y); o.z = f2bf(v.z); o.w = f2bf(v.w);
    *(ushort4*)(af + (size_t)m * 2048 + q) = o;
}

// Pack x [8][64][2048] fp32 -> bf16 (same flat layout; rows = b*64+c)
__global__ __launch_bounds__(256) void pack_xb(const float* __restrict__ x,
                                               unsigned short* __restrict__ xb) {
    int idx = blockIdx.x * 256 + threadIdx.x;
    int q = idx * 4;
    float4 v = *(const float4*)(x + q);
    ushort4 o; o.x = f2bf(v.x); o.y = f2bf(v.y); o.z = f2bf(v.z); o.w = f2bf(v.w);
    *(ushort4*)(xb + q) = o;
}

// Pack Mi [2048 n][8192 k'] bf16:
//  k' in [0,2048)    : Vi_re[n][k']
//  k' in [2048,4096) : -Vi_im[n][k'-2048]
//  k' in [4096,6144) : g=k'-4096, g>=64 ? Vi_re[n][4095-g] : 0
//  k' in [6144,8192) : g=k'-6144, g>=64 ? Vi_im[n][4095-g] : 0
__global__ __launch_bounds__(256) void pack_mi(const float* __restrict__ vi_re,
                                               const float* __restrict__ vi_im,
                                               unsigned short* __restrict__ mi) {
    int idx = blockIdx.x * 256 + threadIdx.x;      // one quad
    int n = idx >> 11;                              // 2048 quads per row
    int q4 = (idx & 2047) * 4;                      // k' base
    int region = q4 >> 11;
    int off = q4 & 2047;
    float4 v;
    if (region == 0) {
        v = *(const float4*)(vi_re + (size_t)n * MFREQ + off);
    } else if (region == 1) {
        float4 t = *(const float4*)(vi_im + (size_t)n * MFREQ + off);
        v.x = -t.x; v.y = -t.y; v.z = -t.z; v.w = -t.w;
    } else {
        if (off < 64) { v.x = v.y = v.z = v.w = 0.0f; }
        else {
            const float* src = (region == 2 ? vi_re : vi_im);
            float4 t = *(const float4*)(src + (size_t)n * MFREQ + (4092 - off));
            v.x = t.w; v.y = t.z; v.z = t.y; v.w = t.x;   // reversed
        }
    }
    ushort4 o; o.x = f2bf(v.x); o.y = f2bf(v.y); o.z = f2bf(v.z); o.w = f2bf(v.w);
    *(ushort4*)(mi + (size_t)n * 8192 + q4) = o;
}

// Transpose weights: wt[g][io][2] fp32 interleaved (re,im).
// g<1024 from w1 (xy=g), g>=1024 from w2 (xy=g-1024). Source [i][o][x][y] = [io][xy].
__global__ __launch_bounds__(256) void pack_wt(const float* __restrict__ w1_re,
                                               const float* __restrict__ w1_im,
                                               const float* __restrict__ w2_re,
                                               const float* __restrict__ w2_im,
                                               float* __restrict__ wt) {
    __shared__ float sre[64][65];
    __shared__ float sim[64][65];
    int wsel = blockIdx.z;
    const float* wre = wsel ? w2_re : w1_re;
    const float* wim = wsel ? w2_im : w1_im;
    int io0 = blockIdx.y * 64, xy0 = blockIdx.x * 64;
    int t = threadIdx.x;
    int r = t >> 2, cq = (t & 3) * 16;
    for (int j = 0; j < 16; j += 4) {
        float4 a = *(const float4*)(wre + (size_t)(io0 + r) * 1024 + xy0 + cq + j);
        float4 b = *(const float4*)(wim + (size_t)(io0 + r) * 1024 + xy0 + cq + j);
        sre[r][cq + j + 0] = a.x; sre[r][cq + j + 1] = a.y; sre[r][cq + j + 2] = a.z; sre[r][cq + j + 3] = a.w;
        sim[r][cq + j + 0] = b.x; sim[r][cq + j + 1] = b.y; sim[r][cq + j + 2] = b.z; sim[r][cq + j + 3] = b.w;
    }
    __syncthreads();
    int iol = t & 63, gq = t >> 6;
    for (int jj = 0; jj < 16; ++jj) {
        int gl = jj * 4 + gq;
        int g = xy0 + gl + wsel * 1024;
        float2 o; o.x = sre[iol][gl]; o.y = sim[iol][gl];
        *(float2*)(wt + ((size_t)g * 4096 + io0 + iol) * 2) = o;
    }
}

// phi[b][g] = sum_e m{1,2}[xy][e] * emb[b][e]   (complex; m1 for g<1024)
__global__ __launch_bounds__(256) void phi_k(const float* __restrict__ m1_re,
                                             const float* __restrict__ m1_im,
                                             const float* __restrict__ m2_re,
                                             const float* __restrict__ m2_im,
                                             const float* __restrict__ emb,
                                             float* __restrict__ phi_re,
                                             float* __restrict__ phi_im) {
    int g = blockIdx.x, b = blockIdx.y, e = threadIdx.x;
    int xy = g & 1023;
    const float* mr = (g < 1024 ? m1_re : m2_re) + xy * 256;
    const float* mi = (g < 1024 ? m1_im : m2_im) + xy * 256;
    float em = emb[b * 256 + e];
    float pr = mr[e] * em, pi = mi[e] * em;
    __shared__ float sr[4], si[4];
    for (int s = 32; s > 0; s >>= 1) { pr += __shfl_down(pr, s); pi += __shfl_down(pi, s); }
    int wid = e >> 6;
    if ((e & 63) == 0) { sr[wid] = pr; si[wid] = pi; }
    __syncthreads();
    if (e == 0) {
        phi_re[b * 2048 + g] = sr[0] + sr[1] + sr[2] + sr[3];
        phi_im[b * 2048 + g] = si[0] + si[1] + si[2] + si[3];
    }
}

// ---------------------------------------------------------------------------
// bf16 MFMA GEMM: C[M][N] = alpha * A[M][K] @ B[N][K]^T  (row-major, K contig)
// Tile 64x64x64, 256 threads (4 waves of 32x32), LDS in fragment-cell order.
#define CELLI(kb, r) ((kb) * 64 + (((r) + (kb)) & 63))

__global__ __launch_bounds__(256) void gemm_bt(const unsigned short* __restrict__ A,
                                               const unsigned short* __restrict__ Bm,
                                               float* __restrict__ Cm,
                                               int M, int N, int K, float alpha) {
    __shared__ uint4 As[512];
    __shared__ uint4 Bs[512];
    int t = threadIdx.x;
    int m0 = blockIdx.y * 64, n0 = blockIdx.x * 64;
    int lane = t & 63, wid = t >> 6;
    int wm = (wid >> 1) * 32, wn = (wid & 1) * 32;
    int quad = lane >> 4, lr = lane & 15;
    int row = t >> 2, ch = t & 3;
    const unsigned short* Arow = A + (size_t)(m0 + row) * K + ch * 8;
    const unsigned short* Brow = Bm + (size_t)(n0 + row) * K + ch * 8;
    f32x4 acc00 = {0.f,0.f,0.f,0.f}, acc01 = {0.f,0.f,0.f,0.f};
    f32x4 acc10 = {0.f,0.f,0.f,0.f}, acc11 = {0.f,0.f,0.f,0.f};

    for (int kk = 0; kk < K; kk += 64) {
        uint4 a0 = *(const uint4*)(Arow + kk);
        uint4 a1 = *(const uint4*)(Arow + kk + 32);
        uint4 b0 = *(const uint4*)(Brow + kk);
        uint4 b1 = *(const uint4*)(Brow + kk + 32);
        __syncthreads();
        As[CELLI(ch, row)]     = a0;
        As[CELLI(ch + 4, row)] = a1;
        Bs[CELLI(ch, row)]     = b0;
        Bs[CELLI(ch + 4, row)] = b1;
        __syncthreads();
        #pragma unroll
        for (int ki = 0; ki < 2; ++ki) {
            int kb = ki * 4 + quad;
            bf16x8 af0 = as_bf16x8(As[CELLI(kb, wm + lr)]);
            bf16x8 af1 = as_bf16x8(As[CELLI(kb, wm + 16 + lr)]);
            bf16x8 bf0 = as_bf16x8(Bs[CELLI(kb, wn + lr)]);
            bf16x8 bf1 = as_bf16x8(Bs[CELLI(kb, wn + 16 + lr)]);
            acc00 = __builtin_amdgcn_mfma_f32_16x16x32_bf16(af0, bf0, acc00, 0, 0, 0);
            acc01 = __builtin_amdgcn_mfma_f32_16x16x32_bf16(af0, bf1, acc01, 0, 0, 0);
            acc10 = __builtin_amdgcn_mfma_f32_16x16x32_bf16(af1, bf0, acc10, 0, 0, 0);
            acc11 = __builtin_amdgcn_mfma_f32_16x16x32_bf16(af1, bf1, acc11, 0, 0, 0);
        }
    }
    // Epilogue: D col = lane&15, row = quad*4 + reg
    f32x4 accs[2][2] = {{acc00, acc01}, {acc10, acc11}};
    #pragma unroll
    for (int mi2 = 0; mi2 < 2; ++mi2)
    #pragma unroll
    for (int ni2 = 0; ni2 < 2; ++ni2) {
        int rr = m0 + wm + mi2 * 16 + quad * 4;
        int cc = n0 + wn + ni2 * 16 + lr;
        float* cp = Cm + (size_t)rr * N + cc;
        f32x4 v = accs[mi2][ni2];
        cp[0]           = v.x * alpha;
        cp[(size_t)N]   = v.y * alpha;
        cp[(size_t)2*N] = v.z * alpha;
        cp[(size_t)3*N] = v.w * alpha;
    }
}

// ---------------------------------------------------------------------------
// Middle: per mode g, complex out[o] = phi * sum_i in[i]*W[i][o]; scatter to Yt
// Yt rows = b*64+c, cols k' in [0,8192); regions per Hermitian fold.
__global__ __launch_bounds__(256) void middle_k(const float* __restrict__ O1,
                                                const float* __restrict__ wt,
                                                const float* __restrict__ phi_re,
                                                const float* __restrict__ phi_im,
                                                unsigned short* __restrict__ Yt) {
    __shared__ float2 wts[4096];
    __shared__ float2 inc[512];
    int g = blockIdx.x, t = threadIdx.x;
    const float2* wg = (const float2*)wt + (size_t)g * 4096;
    #pragma unroll
    for (int j = 0; j < 16; ++j) wts[t + 256 * j] = wg[t + 256 * j];
    #pragma unroll
    for (int j = 0; j < 2; ++j) {
        int idx = t + 256 * j;
        float2 a; a.x = O1[(size_t)g * 512 + idx]; a.y = O1[(size_t)(2048 + g) * 512 + idx];
        inc[idx] = a;
    }
    __syncthreads();
    int b = t >> 5, oo = t & 31;
    float ar0 = 0.f, ai0 = 0.f, ar1 = 0.f, ai1 = 0.f;
    #pragma unroll 8
    for (int i = 0; i < 64; ++i) {
        float2 a = inc[b * 64 + i];
        float2 w0 = wts[i * 64 + oo];
        float2 w1 = wts[i * 64 + oo + 32];
        ar0 += a.x * w0.x - a.y * w0.y;  ai0 += a.x * w0.y + a.y * w0.x;
        ar1 += a.x * w1.x - a.y * w1.y;  ai1 += a.x * w1.y + a.y * w1.x;
    }
    float pr = phi_re[b * 2048 + g], pi = phi_im[b * 2048 + g];
    float yr0 = pr * ar0 - pi * ai0, yi0 = pr * ai0 + pi * ar0;
    float yr1 = pr * ar1 - pi * ai1, yi1 = pr * ai1 + pi * ar1;
    {
        size_t r0 = (size_t)(b * 64 + oo) * 8192;
        size_t rf = (size_t)(b * 64 + 63 - oo) * 8192;
        Yt[r0 + g]        = f2bf(yr0);
        Yt[r0 + 2048 + g] = f2bf(yi0);
        Yt[rf + 4096 + g] = f2bf(yr0);
        Yt[rf + 6144 + g] = f2bf(yi0);
    }
    {
        int o = oo + 32;
        size_t r0 = (size_t)(b * 64 + o) * 8192;
        size_t rf = (size_t)(b * 64 + 63 - o) * 8192;
        Yt[r0 + g]        = f2bf(yr1);
        Yt[r0 + 2048 + g] = f2bf(yi1);
        Yt[rf + 4096 + g] = f2bf(yr1);
        Yt[rf + 6144 + g] = f2bf(yi1);
    }
}

// ---------------------------------------------------------------------------
extern "C" void kernel_launch(void* const* d_in, const int* in_sizes, int n_in,
                              void* d_out, int out_size, void* d_ws, size_t ws_size,
                              hipStream_t stream) {
    const float* x     = (const float*)d_in[0];
    const float* emb   = (const float*)d_in[1];
    const float* vf_re = (const float*)d_in[2];
    const float* vf_im = (const float*)d_in[3];
    const float* vi_re = (const float*)d_in[4];
    const float* vi_im = (const float*)d_in[5];
    const float* w1_re = (const float*)d_in[6];
    const float* w1_im = (const float*)d_in[7];
    const float* w2_re = (const float*)d_in[8];
    const float* w2_im = (const float*)d_in[9];
    const float* m1_re = (const float*)d_in[10];
    const float* m1_im = (const float*)d_in[11];
    const float* m2_re = (const float*)d_in[12];
    const float* m2_im = (const float*)d_in[13];

    char* ws = (char*)d_ws;
    unsigned short* Af = (unsigned short*)(ws);                 // 16,777,216 B
    unsigned short* Xb = (unsigned short*)(ws + 16777216);      //  2,097,152 B
    unsigned short* Mi = (unsigned short*)(ws + 18874368);      // 33,554,432 B
    float*          Wt = (float*)(ws + 52428800);               // 67,108,864 B
    float*          O1 = (float*)(ws + 119537664);              //  8,388,608 B
    float*       PhiRe = (float*)(ws + 127926272);              //     65,536 B
    float*       PhiIm = (float*)(ws + 127991808);              //     65,536 B
    unsigned short* Yt = (unsigned short*)(ws + 128057344);     //  8,388,608 B -> 136,445,952 total
    float* out = (float*)d_out;

    pack_af<<<8192, 256, 0, stream>>>(vf_re, vf_im, Af);
    pack_xb<<<1024, 256, 0, stream>>>(x, Xb);
    pack_mi<<<16384, 256, 0, stream>>>(vi_re, vi_im, Mi);
    pack_wt<<<dim3(16, 64, 2), 256, 0, stream>>>(w1_re, w1_im, w2_re, w2_im, Wt);
    phi_k<<<dim3(2048, 8), 256, 0, stream>>>(m1_re, m1_im, m2_re, m2_im, emb, PhiRe, PhiIm);

    // Forward: O1[4096][512] = Af[4096x2048] @ Xb[512x2048]^T
    gemm_bt<<<dim3(8, 64), 256, 0, stream>>>(Af, Xb, O1, 4096, 512, 2048, 1.0f);

    middle_k<<<2048, 256, 0, stream>>>(O1, Wt, PhiRe, PhiIm, Yt);

    // Inverse: out[512][2048] = (2/N) * Yt[512x8192] @ Mi[2048x8192]^T
    gemm_bt<<<dim3(32, 8), 256, 0, stream>>>(Yt, Mi, out, 512, 2048, 8192, 1.0f / 1024.0f);
}

// Round 2
// 325.707 us; speedup vs baseline: 1.2065x; 1.2065x over previous
//
#include <hip/hip_runtime.h>

#define BB    8
#define CC    64
#define NN    2048
#define GG    2048
#define MFREQ 4032

typedef __attribute__((ext_vector_type(4))) float f32x4;
typedef __attribute__((ext_vector_type(8))) short bf16x8;

static __device__ __forceinline__ unsigned short f2bf(float f) {
    union { float f; unsigned u; } v; v.f = f;
    unsigned r = v.u + 0x7fff + ((v.u >> 16) & 1);   // RNE
    return (unsigned short)(r >> 16);
}

static __device__ __forceinline__ bf16x8 as_bf16x8(uint4 u) {
    union { uint4 u; bf16x8 b; } v; v.u = u; return v.b;
}

#define ASYNC_COPY16(gp, lp)                                                        \
    __builtin_amdgcn_global_load_lds(                                               \
        (const __attribute__((address_space(1))) unsigned int*)(gp),                \
        (__attribute__((address_space(3))) unsigned int*)(lp), 16, 0, 0)

// ---------------------------------------------------------------------------
// Pack Af [4096 x 2048] bf16: rows 0..2047 = Vf_re[f(g)], rows 2048.. = Vf_im
__global__ __launch_bounds__(256) void pack_af(const float* __restrict__ vf_re,
                                               const float* __restrict__ vf_im,
                                               unsigned short* __restrict__ af) {
    int idx = blockIdx.x * 256 + threadIdx.x;
    int m = idx >> 9;
    int q = (idx & 511) * 4;
    int g = m & 2047;
    int f = (g >> 5) * 63 + (g & 31);
    const float* src = (m < 2048 ? vf_re : vf_im) + (size_t)f * 2048 + q;
    float4 v = *(const float4*)src;
    ushort4 o; o.x = f2bf(v.x); o.y = f2bf(v.y); o.z = f2bf(v.z); o.w = f2bf(v.w);
    *(ushort4*)(af + (size_t)m * 2048 + q) = o;
}

__global__ __launch_bounds__(256) void pack_xb(const float* __restrict__ x,
                                               unsigned short* __restrict__ xb) {
    int idx = blockIdx.x * 256 + threadIdx.x;
    int q = idx * 4;
    float4 v = *(const float4*)(x + q);
    ushort4 o; o.x = f2bf(v.x); o.y = f2bf(v.y); o.z = f2bf(v.z); o.w = f2bf(v.w);
    *(ushort4*)(xb + q) = o;
}

// Pack Mi [2048 n][8192 k'] bf16 (Hermitian fold baked in)
__global__ __launch_bounds__(256) void pack_mi(const float* __restrict__ vi_re,
                                               const float* __restrict__ vi_im,
                                               unsigned short* __restrict__ mi) {
    int idx = blockIdx.x * 256 + threadIdx.x;
    int n = idx >> 11;
    int q4 = (idx & 2047) * 4;
    int region = q4 >> 11;
    int off = q4 & 2047;
    float4 v;
    if (region == 0) {
        v = *(const float4*)(vi_re + (size_t)n * MFREQ + off);
    } else if (region == 1) {
        float4 t = *(const float4*)(vi_im + (size_t)n * MFREQ + off);
        v.x = -t.x; v.y = -t.y; v.z = -t.z; v.w = -t.w;
    } else {
        if (off < 64) { v.x = v.y = v.z = v.w = 0.0f; }
        else {
            const float* src = (region == 2 ? vi_re : vi_im);
            float4 t = *(const float4*)(src + (size_t)n * MFREQ + (4092 - off));
            v.x = t.w; v.y = t.z; v.z = t.y; v.w = t.x;
        }
    }
    ushort4 o; o.x = f2bf(v.x); o.y = f2bf(v.y); o.z = f2bf(v.z); o.w = f2bf(v.w);
    *(ushort4*)(mi + (size_t)n * 8192 + q4) = o;
}

// Transpose weights: wt[g][io] = packed bf16 (re | im<<16)
__global__ __launch_bounds__(256) void pack_wt(const float* __restrict__ w1_re,
                                               const float* __restrict__ w1_im,
                                               const float* __restrict__ w2_re,
                                               const float* __restrict__ w2_im,
                                               unsigned int* __restrict__ wt) {
    __shared__ float sre[64][65];
    __shared__ float sim[64][65];
    int wsel = blockIdx.z;
    const float* wre = wsel ? w2_re : w1_re;
    const float* wim = wsel ? w2_im : w1_im;
    int io0 = blockIdx.y * 64, xy0 = blockIdx.x * 64;
    int t = threadIdx.x;
    int r = t >> 2, cq = (t & 3) * 16;
    for (int j = 0; j < 16; j += 4) {
        float4 a = *(const float4*)(wre + (size_t)(io0 + r) * 1024 + xy0 + cq + j);
        float4 b = *(const float4*)(wim + (size_t)(io0 + r) * 1024 + xy0 + cq + j);
        sre[r][cq + j + 0] = a.x; sre[r][cq + j + 1] = a.y; sre[r][cq + j + 2] = a.z; sre[r][cq + j + 3] = a.w;
        sim[r][cq + j + 0] = b.x; sim[r][cq + j + 1] = b.y; sim[r][cq + j + 2] = b.z; sim[r][cq + j + 3] = b.w;
    }
    __syncthreads();
    int iol = t & 63, gq = t >> 6;
    for (int jj = 0; jj < 16; ++jj) {
        int gl = jj * 4 + gq;
        int g = xy0 + gl + wsel * 1024;
        unsigned int o = (unsigned int)f2bf(sre[iol][gl]) | ((unsigned int)f2bf(sim[iol][gl]) << 16);
        wt[(size_t)g * 4096 + io0 + iol] = o;
    }
}

// phi[b][g] = sum_e m{1,2}[xy][e] * emb[b][e]
__global__ __launch_bounds__(256) void phi_k(const float* __restrict__ m1_re,
                                             const float* __restrict__ m1_im,
                                             const float* __restrict__ m2_re,
                                             const float* __restrict__ m2_im,
                                             const float* __restrict__ emb,
                                             float* __restrict__ phi_re,
                                             float* __restrict__ phi_im) {
    int g = blockIdx.x, b = blockIdx.y, e = threadIdx.x;
    int xy = g & 1023;
    const float* mr = (g < 1024 ? m1_re : m2_re) + xy * 256;
    const float* mi = (g < 1024 ? m1_im : m2_im) + xy * 256;
    float em = emb[b * 256 + e];
    float pr = mr[e] * em, pi = mi[e] * em;
    __shared__ float sr[4], si[4];
    for (int s = 32; s > 0; s >>= 1) { pr += __shfl_down(pr, s); pi += __shfl_down(pi, s); }
    int wid = e >> 6;
    if ((e & 63) == 0) { sr[wid] = pr; si[wid] = pi; }
    __syncthreads();
    if (e == 0) {
        phi_re[b * 2048 + g] = sr[0] + sr[1] + sr[2] + sr[3];
        phi_im[b * 2048 + g] = si[0] + si[1] + si[2] + si[3];
    }
}

// ---------------------------------------------------------------------------
// Split-K MFMA GEMM: P[z][M][N] += A[M][K-slice] @ B[N][K-slice]^T
// 128x128 tile, BK=64, global_load_lds(16B) staging, XOR-swizzled source fetch.
__global__ __launch_bounds__(256, 2) void gemm_sk(const unsigned short* __restrict__ A,
                                                  const unsigned short* __restrict__ Bm,
                                                  float* __restrict__ P,
                                                  int M, int N, int K, int Kper) {
    __shared__ unsigned short As[128 * 64];
    __shared__ unsigned short Bs[128 * 64];
    int t = threadIdx.x;
    int lane = t & 63, w = t >> 6;
    int m0 = blockIdx.y * 128, n0 = blockIdx.x * 128;
    int z = blockIdx.z;
    int kbase = z * Kper;
    int wm = (w >> 1) * 64, wn = (w & 1) * 64;
    int lr = lane & 15, quad = lane >> 4;
    int rsub = lane >> 3, slot = lane & 7;

    f32x4 acc[4][4] = {};

    for (int kk = kbase; kk < kbase + Kper; kk += 64) {
        __syncthreads();
        #pragma unroll
        for (int l = 0; l < 4; ++l) {
            int r = (w * 4 + l) * 8 + rsub;
            int c = slot ^ (r & 7);
            ASYNC_COPY16(A + (size_t)(m0 + r) * K + kk + c * 8, As + r * 64 + slot * 8);
            ASYNC_COPY16(Bm + (size_t)(n0 + r) * K + kk + c * 8, Bs + r * 64 + slot * 8);
        }
        __syncthreads();
        #pragma unroll
        for (int ks = 0; ks < 2; ++ks) {
            bf16x8 af[4], bfr[4];
            #pragma unroll
            for (int i = 0; i < 4; ++i) {
                int row = wm + i * 16 + lr;
                int q = (ks * 4 + quad) ^ (row & 7);
                af[i] = *(const bf16x8*)(As + row * 64 + q * 8);
                int rowb = wn + i * 16 + lr;
                int qb = (ks * 4 + quad) ^ (rowb & 7);
                bfr[i] = *(const bf16x8*)(Bs + rowb * 64 + qb * 8);
            }
            #pragma unroll
            for (int i = 0; i < 4; ++i)
            #pragma unroll
            for (int j = 0; j < 4; ++j)
                acc[i][j] = __builtin_amdgcn_mfma_f32_16x16x32_bf16(af[i], bfr[j], acc[i][j], 0, 0, 0);
        }
    }
    float* Pz = P + (size_t)z * M * N;
    #pragma unroll
    for (int i = 0; i < 4; ++i)
    #pragma unroll
    for (int j = 0; j < 4; ++j) {
        int rr = m0 + wm + i * 16 + quad * 4;
        int cc = n0 + wn + j * 16 + lr;
        float* cp = Pz + (size_t)rr * N + cc;
        f32x4 v = acc[i][j];
        cp[0]             = v.x;
        cp[(size_t)N]     = v.y;
        cp[2 * (size_t)N] = v.z;
        cp[3 * (size_t)N] = v.w;
    }
}

// Sum split-K partials: out[i] = alpha * sum_z P[z][i]
__global__ __launch_bounds__(256) void reduce_k(const float* __restrict__ P,
                                                float* __restrict__ out,
                                                int S, size_t elems, float alpha) {
    size_t idx = ((size_t)blockIdx.x * 256 + threadIdx.x) * 4;
    float4 s = *(const float4*)(P + idx);
    for (int zz = 1; zz < S; ++zz) {
        float4 v = *(const float4*)(P + (size_t)zz * elems + idx);
        s.x += v.x; s.y += v.y; s.z += v.z; s.w += v.w;
    }
    s.x *= alpha; s.y *= alpha; s.z *= alpha; s.w *= alpha;
    *(float4*)(out + idx) = s;
}

// ---------------------------------------------------------------------------
// Middle: per mode g, complex out[o] = phi * sum_i in[i]*W[i][o]; scatter to Yt
__global__ __launch_bounds__(256) void middle_k(const float* __restrict__ O1,
                                                const unsigned int* __restrict__ wt,
                                                const float* __restrict__ phi_re,
                                                const float* __restrict__ phi_im,
                                                unsigned short* __restrict__ Yt) {
    __shared__ unsigned int wts[4096];
    __shared__ float2 inc[512];
    int g = blockIdx.x, t = threadIdx.x;
    const uint4* wg4 = (const uint4*)(wt + (size_t)g * 4096);
    #pragma unroll
    for (int j = 0; j < 4; ++j) ((uint4*)wts)[t + 256 * j] = wg4[t + 256 * j];
    #pragma unroll
    for (int j = 0; j < 2; ++j) {
        int idx = t + 256 * j;
        float2 a; a.x = O1[(size_t)g * 512 + idx]; a.y = O1[(size_t)(2048 + g) * 512 + idx];
        inc[idx] = a;
    }
    __syncthreads();
    int b = t >> 5, oo = t & 31;
    float ar0 = 0.f, ai0 = 0.f, ar1 = 0.f, ai1 = 0.f;
    #pragma unroll 8
    for (int i = 0; i < 64; ++i) {
        float2 a = inc[b * 64 + i];
        unsigned int u0 = wts[i * 64 + oo];
        unsigned int u1 = wts[i * 64 + oo + 32];
        float w0r = __uint_as_float(u0 << 16);
        float w0i = __uint_as_float(u0 & 0xffff0000u);
        float w1r = __uint_as_float(u1 << 16);
        float w1i = __uint_as_float(u1 & 0xffff0000u);
        ar0 += a.x * w0r - a.y * w0i;  ai0 += a.x * w0i + a.y * w0r;
        ar1 += a.x * w1r - a.y * w1i;  ai1 += a.x * w1i + a.y * w1r;
    }
    float pr = phi_re[b * 2048 + g], pi = phi_im[b * 2048 + g];
    float yr0 = pr * ar0 - pi * ai0, yi0 = pr * ai0 + pi * ar0;
    float yr1 = pr * ar1 - pi * ai1, yi1 = pr * ai1 + pi * ar1;
    {
        size_t r0 = (size_t)(b * 64 + oo) * 8192;
        size_t rf = (size_t)(b * 64 + 63 - oo) * 8192;
        Yt[r0 + g]        = f2bf(yr0);
        Yt[r0 + 2048 + g] = f2bf(yi0);
        Yt[rf + 4096 + g] = f2bf(yr0);
        Yt[rf + 6144 + g] = f2bf(yi0);
    }
    {
        int o = oo + 32;
        size_t r0 = (size_t)(b * 64 + o) * 8192;
        size_t rf = (size_t)(b * 64 + 63 - o) * 8192;
        Yt[r0 + g]        = f2bf(yr1);
        Yt[r0 + 2048 + g] = f2bf(yi1);
        Yt[rf + 4096 + g] = f2bf(yr1);
        Yt[rf + 6144 + g] = f2bf(yi1);
    }
}

// ---------------------------------------------------------------------------
extern "C" void kernel_launch(void* const* d_in, const int* in_sizes, int n_in,
                              void* d_out, int out_size, void* d_ws, size_t ws_size,
                              hipStream_t stream) {
    const float* x     = (const float*)d_in[0];
    const float* emb   = (const float*)d_in[1];
    const float* vf_re = (const float*)d_in[2];
    const float* vf_im = (const float*)d_in[3];
    const float* vi_re = (const float*)d_in[4];
    const float* vi_im = (const float*)d_in[5];
    const float* w1_re = (const float*)d_in[6];
    const float* w1_im = (const float*)d_in[7];
    const float* w2_re = (const float*)d_in[8];
    const float* w2_im = (const float*)d_in[9];
    const float* m1_re = (const float*)d_in[10];
    const float* m1_im = (const float*)d_in[11];
    const float* m2_re = (const float*)d_in[12];
    const float* m2_im = (const float*)d_in[13];

    char* ws = (char*)d_ws;
    unsigned short* Af = (unsigned short*)(ws);                 // 16,777,216
    unsigned short* Xb = (unsigned short*)(ws + 16777216);      //  2,097,152
    unsigned short* Mi = (unsigned short*)(ws + 18874368);      // 33,554,432
    unsigned int*   Wt = (unsigned int*)(ws + 52428800);        // 33,554,432 (bf16 pairs)
    float*          O1 = (float*)(ws + 85983232);               //  8,388,608
    float*       PhiRe = (float*)(ws + 94371840);               //     65,536
    float*       PhiIm = (float*)(ws + 94437376);               //     65,536
    unsigned short* Yt = (unsigned short*)(ws + 94502912);      //  8,388,608
    float*          P  = (float*)(ws + 102891520);              // 33,554,432 (shared partials) -> 136,445,952
    float* out = (float*)d_out;

    pack_af<<<8192, 256, 0, stream>>>(vf_re, vf_im, Af);
    pack_xb<<<1024, 256, 0, stream>>>(x, Xb);
    pack_mi<<<16384, 256, 0, stream>>>(vi_re, vi_im, Mi);
    pack_wt<<<dim3(16, 64, 2), 256, 0, stream>>>(w1_re, w1_im, w2_re, w2_im, Wt);
    phi_k<<<dim3(2048, 8), 256, 0, stream>>>(m1_re, m1_im, m2_re, m2_im, emb, PhiRe, PhiIm);

    // Forward: O1[4096][512] = Af[4096x2048] @ Xb[512x2048]^T, split-K 4
    gemm_sk<<<dim3(4, 32, 4), 256, 0, stream>>>(Af, Xb, P, 4096, 512, 2048, 512);
    reduce_k<<<2048, 256, 0, stream>>>(P, O1, 4, (size_t)4096 * 512, 1.0f);

    middle_k<<<2048, 256, 0, stream>>>(O1, Wt, PhiRe, PhiIm, Yt);

    // Inverse: out[512][2048] = (2/N) * Yt[512x8192] @ Mi[2048x8192]^T, split-K 8
    gemm_sk<<<dim3(16, 4, 8), 256, 0, stream>>>(Yt, Mi, P, 512, 2048, 8192, 1024);
    reduce_k<<<1024, 256, 0, stream>>>(P, out, 8, (size_t)512 * 2048, 1.0f / 1024.0f);
}